// Round 6
// baseline (7992.266 us; speedup 1.0000x reference)
//
#include <hip/hip_runtime.h>

#define TT 512
#define BB 64
#define II 1024
#define HH 1024
#define GG 4096   /* 4*H */
#define BH 65536  /* B*H */
#define NBLK 64

typedef __attribute__((ext_vector_type(8))) short bf16x8;
typedef __attribute__((ext_vector_type(4))) float f32x4;

// flag-array sense barrier state (.bss; parity restored every replay via even barrier count)
__device__ unsigned g_sense2;
__device__ unsigned g_flags[NBLK * 16];   // one 64B line per block

__device__ __forceinline__ float bf2f(unsigned short u) {
  union { unsigned int i; float f; } v; v.i = ((unsigned int)u) << 16; return v.f;
}
__device__ __forceinline__ unsigned short f2bf(float f) {
  union { float f; unsigned int i; } v; v.f = f;
  return (unsigned short)((v.i + 0x7FFFu + ((v.i >> 16) & 1u)) >> 16);
}
__device__ __forceinline__ bf16x8 pack8(float4 a, float4 b) {
  union { bf16x8 v; unsigned short u[8]; } p;
  p.u[0] = f2bf(a.x); p.u[1] = f2bf(a.y); p.u[2] = f2bf(a.z); p.u[3] = f2bf(a.w);
  p.u[4] = f2bf(b.x); p.u[5] = f2bf(b.y); p.u[6] = f2bf(b.z); p.u[7] = f2bf(b.w);
  return p.v;
}
__device__ __forceinline__ float sigmoid_f(float x) { return 1.0f / (1.0f + __expf(-x)); }
__device__ __forceinline__ float tanh_f(float x) {
  float e = __expf(-2.0f * fabsf(x));
  float t = (1.0f - e) / (1.0f + e);
  return copysignf(t, x);
}

__device__ __forceinline__ unsigned long long ldq_cohere(const unsigned long long* p) {
  return __hip_atomic_load(p, __ATOMIC_RELAXED, __HIP_MEMORY_SCOPE_AGENT);
}
__device__ __forceinline__ void stq_cohere(unsigned long long* p, unsigned long long v) {
  __hip_atomic_store(p, v, __ATOMIC_RELAXED, __HIP_MEMORY_SCOPE_AGENT);
}

// Fence-free flag-array sense-reversal barrier over NBLK blocks.
// All cross-block data (hbuf, flags) travels via agent-scope atomics that bypass
// L1/L2, so no cache fences are needed; L2 stays warm for gx/W/out.
// __syncthreads drains each wave's vmcnt (stores acked at coherence point) before
// tid0's release-store of the flag.
__device__ __forceinline__ void grid_barrier3(unsigned tgt) {
  __syncthreads();
  const int tid = threadIdx.x;
  if (tid == 0)
    __hip_atomic_store(&g_flags[blockIdx.x * 16], tgt, __ATOMIC_RELEASE, __HIP_MEMORY_SCOPE_AGENT);
  if (blockIdx.x == 0) {
    if (tid < NBLK) {      // wave 0: one lane polls one block's flag
      const unsigned* fp = &g_flags[tid * 16];
      while (__hip_atomic_load(fp, __ATOMIC_RELAXED, __HIP_MEMORY_SCOPE_AGENT) != tgt)
        __builtin_amdgcn_s_sleep(1);
    }
    __syncthreads();
    if (tid == 0)
      __hip_atomic_store(&g_sense2, tgt, __ATOMIC_RELEASE, __HIP_MEMORY_SCOPE_AGENT);
  } else {
    if (tid == 0) {
      while (__hip_atomic_load(&g_sense2, __ATOMIC_RELAXED, __HIP_MEMORY_SCOPE_AGENT) != tgt)
        __builtin_amdgcn_s_sleep(1);
    }
    __syncthreads();
  }
}

// ---------------- input GEMM chunk ----------------
// gxc[m][n] = sum_k xc[m][k]*w_ih[n][k] + b_ih[n] + b_hh[n], m in [0, tc*64)
__global__ __launch_bounds__(256) void wdlstm_gemm_gx(
    const float* __restrict__ xc, const float* __restrict__ w_ih,
    const float* __restrict__ b_ih, const float* __restrict__ b_hh,
    unsigned short* __restrict__ gxc) {
  __shared__ __align__(16) char As[16384];  // [128][64] bf16, XOR-swizzled
  __shared__ __align__(16) char Bs[16384];

  const int tid = threadIdx.x;
  const int bx  = blockIdx.x;
  const int tm  = bx >> 5, tn = bx & 31;
  const int m0  = tm * 128, n0 = tn * 128;
  const int wv  = tid >> 6, l = tid & 63;
  const int wr  = wv >> 1, wc = wv & 1;
  const int ln  = l & 15, lq = l >> 4;

  f32x4 acc[4][4];
#pragma unroll
  for (int i = 0; i < 4; ++i)
#pragma unroll
    for (int j = 0; j < 4; ++j) acc[i][j] = (f32x4){0.f, 0.f, 0.f, 0.f};

  for (int kt = 0; kt < 16; ++kt) {
    const int k0 = kt * 64;
    __syncthreads();
#pragma unroll
    for (int o = 0; o < 4; ++o) {
      int c2 = tid + 256 * o;        // 1024 16B-chunks
      int row = c2 >> 3, q8 = c2 & 7;
      int addr = (row * 128 + q8 * 16) ^ ((row & 7) << 4);
      {
        const float* s = xc + (size_t)(m0 + row) * II + k0 + q8 * 8;
        float4 a0 = *(const float4*)s;
        float4 a1 = *(const float4*)(s + 4);
        *(bf16x8*)(As + addr) = pack8(a0, a1);
      }
      {
        const float* s = w_ih + (size_t)(n0 + row) * II + k0 + q8 * 8;
        float4 a0 = *(const float4*)s;
        float4 a1 = *(const float4*)(s + 4);
        *(bf16x8*)(Bs + addr) = pack8(a0, a1);
      }
    }
    __syncthreads();
#pragma unroll
    for (int kc = 0; kc < 2; ++kc) {
      bf16x8 af[4], bfr[4];
#pragma unroll
      for (int mi = 0; mi < 4; ++mi) {
        int row = 64 * wr + 16 * mi + ln;
        int addr = (row * 128 + kc * 64 + lq * 16) ^ ((row & 7) << 4);
        af[mi] = *(const bf16x8*)(As + addr);
      }
#pragma unroll
      for (int ni = 0; ni < 4; ++ni) {
        int row = 64 * wc + 16 * ni + ln;
        int addr = (row * 128 + kc * 64 + lq * 16) ^ ((row & 7) << 4);
        bfr[ni] = *(const bf16x8*)(Bs + addr);
      }
#pragma unroll
      for (int mi = 0; mi < 4; ++mi)
#pragma unroll
        for (int ni = 0; ni < 4; ++ni)
          acc[mi][ni] = __builtin_amdgcn_mfma_f32_16x16x32_bf16(af[mi], bfr[ni], acc[mi][ni], 0, 0, 0);
    }
  }
#pragma unroll
  for (int mi = 0; mi < 4; ++mi)
#pragma unroll
    for (int ni = 0; ni < 4; ++ni) {
      int col = n0 + 64 * wc + 16 * ni + ln;
      float bv = b_ih[col] + b_hh[col];
#pragma unroll
      for (int r = 0; r < 4; ++r) {
        int row = m0 + 64 * wr + 16 * mi + 4 * lq + r;
        gxc[(size_t)row * GG + col] = f2bf(acc[mi][ni][r] + bv);
      }
    }
}

// ---------------- recurrence over one time-chunk [t0, t0+tc) ----------------
// 64 WGs x 256 threads (4 waves). WG owns 16 h-cols (64 gate cols g*16+jj).
// Masked W slice (64x1024 bf16, 128 KB) in LDS for the whole chunk.
// Per step: wave wv computes D rows b=16wv..16wv+15 x all 64 gate cols (128 MFMA).
// h broadcast via bf16x4-packed u64 agent-atomics in hbuf (ping-pong); no fences.
__global__ __launch_bounds__(256) void wdlstm_recurrence(
    const float* __restrict__ w_hh, const float* __restrict__ hh_mask,
    const unsigned short* __restrict__ gxc,
    float* __restrict__ out, float* __restrict__ c_state,
    unsigned long long* __restrict__ hbuf,   // [2][BH/4] packed bf16x4
    int t0, int tc, unsigned sense0, int tail_bar) {
  __shared__ __align__(16) char Wlds[131072];    // [64][1024] bf16, XOR-swizzled
  __shared__ float Dlds[64][67];                 // 64x64 D, pad 67 (~2-way banks)

  const int tid = threadIdx.x;
  const int wv  = tid >> 6, l = tid & 63;
  const int ln  = l & 15, lq = l >> 4;
  const int j0  = blockIdx.x * 16;

  // preload masked W slice: LDS row n (0..63) = w_hh row (n>>4)*H + j0 + (n&15)
#pragma unroll
  for (int c8 = 0; c8 < 32; ++c8) {
    int c = tid + 256 * c8;          // 8192 chunks of 8 elems
    int n = c >> 7, cc = c & 127;
    int wrow = (n >> 4) * HH + j0 + (n & 15);
    const float* sw = w_hh   + (size_t)wrow * HH + cc * 8;
    const float* sm = hh_mask + (size_t)wrow * HH + cc * 8;
    float4 w0 = *(const float4*)sw, w1 = *(const float4*)(sw + 4);
    float4 m0 = *(const float4*)sm, m1 = *(const float4*)(sm + 4);
    float4 p0 = {w0.x * m0.x, w0.y * m0.y, w0.z * m0.z, w0.w * m0.w};
    float4 p1 = {w1.x * m1.x, w1.y * m1.y, w1.z * m1.z, w1.w * m1.w};
    int addr = (n * 2048 + cc * 16) ^ ((n & 7) << 4);
    *(bf16x8*)(Wlds + addr) = pack8(p0, p1);
  }
  __syncthreads();

  // elementwise ownership: thread -> (b = tid&63, jj = (tid>>6)*4 + q, q=0..3)
  const int b_ep  = tid & 63;
  const int jgrp  = tid >> 6;
  const int jj0   = jgrp * 4;
  float c_reg[4];
  if (t0 == 0) {
    c_reg[0] = c_reg[1] = c_reg[2] = c_reg[3] = 0.f;
  } else {
    float4 cv = *(const float4*)(c_state + (size_t)b_ep * HH + j0 + jj0);
    c_reg[0] = cv.x; c_reg[1] = cv.y; c_reg[2] = cv.z; c_reg[3] = cv.w;
  }
  unsigned cur = sense0;

  float* hn_out = out + (size_t)TT * BH;
  float* cn_out = hn_out + BH;

  // prefetch gx for lt=0: 4 gates x 4 consecutive j  (plain cached u64 loads)
  float gxv[4][4];
#pragma unroll
  for (int g = 0; g < 4; ++g) {
    unsigned long long u = *(const unsigned long long*)(gxc + (size_t)b_ep * GG + g * HH + j0 + jj0);
#pragma unroll
    for (int q = 0; q < 4; ++q) gxv[g][q] = bf2f((unsigned short)(u >> (16 * q)));
  }

  for (int lt = 0; lt < tc; ++lt) {
    const int t = t0 + lt;
    const unsigned long long* hb_prev = hbuf + (size_t)((t ^ 1) & 1) * (BH / 4);
    unsigned long long*       hb_cur  = hbuf + (size_t)(t & 1) * (BH / 4);

    // ---- recurrent GEMM: D(64x64) = h_prev(64x1024) @ Wslice^T; h(-1)=0 -> D=0
    f32x4 acc[4];
#pragma unroll
    for (int ni = 0; ni < 4; ++ni) acc[ni] = (f32x4){0.f, 0.f, 0.f, 0.f};
    if (t > 0) {
      const size_t arow = (size_t)(16 * wv + ln) * 256;   // u64 index of h row
#pragma unroll 4
      for (int kc = 0; kc < 32; ++kc) {
        union { bf16x8 v; unsigned long long q[2]; } a;
        size_t ai = arow + kc * 8 + lq * 2;
        a.q[0] = ldq_cohere(hb_prev + ai);
        a.q[1] = ldq_cohere(hb_prev + ai + 1);
#pragma unroll
        for (int ni = 0; ni < 4; ++ni) {
          int n = 16 * ni + ln;
          int baddr = (n * 2048 + kc * 64 + lq * 16) ^ ((n & 7) << 4);
          bf16x8 b = *(const bf16x8*)(Wlds + baddr);
          acc[ni] = __builtin_amdgcn_mfma_f32_16x16x32_bf16(a.v, b, acc[ni], 0, 0, 0);
        }
      }
    }
    // transpose D through LDS: wave wv rows 16wv+4lq+r, cols 16ni+ln
#pragma unroll
    for (int ni = 0; ni < 4; ++ni)
#pragma unroll
      for (int r = 0; r < 4; ++r)
        Dlds[16 * wv + 4 * lq + r][16 * ni + ln] = acc[ni][r];
    __syncthreads();

    // ---- elementwise: 4 states per thread
    float hq[4];
#pragma unroll
    for (int q = 0; q < 4; ++q) {
      float g0 = Dlds[b_ep][ 0 + jj0 + q] + gxv[0][q];
      float g1 = Dlds[b_ep][16 + jj0 + q] + gxv[1][q];
      float g2 = Dlds[b_ep][32 + jj0 + q] + gxv[2][q];
      float g3 = Dlds[b_ep][48 + jj0 + q] + gxv[3][q];
      float ig = sigmoid_f(g0);
      float fg = sigmoid_f(g1);
      float gg = tanh_f(g2);
      float og = sigmoid_f(g3);
      c_reg[q] = fg * c_reg[q] + ig * gg;
      hq[q] = og * tanh_f(c_reg[q]);
    }
    float4 hv = {hq[0], hq[1], hq[2], hq[3]};
    *(float4*)(out + (size_t)t * BH + (size_t)b_ep * HH + j0 + jj0) = hv;
    unsigned long long hpack =  (unsigned long long)f2bf(hq[0])
                             | ((unsigned long long)f2bf(hq[1]) << 16)
                             | ((unsigned long long)f2bf(hq[2]) << 32)
                             | ((unsigned long long)f2bf(hq[3]) << 48);
    stq_cohere(hb_cur + ((size_t)b_ep * HH + j0 + jj0) / 4, hpack);
    if (t == TT - 1) {
      *(float4*)(hn_out + (size_t)b_ep * HH + j0 + jj0) = hv;
      float4 cv = {c_reg[0], c_reg[1], c_reg[2], c_reg[3]};
      *(float4*)(cn_out + (size_t)b_ep * HH + j0 + jj0) = cv;
    }

    // prefetch next step's gx into registers (survives barrier), then sync
    if (lt + 1 < tc) {
#pragma unroll
      for (int g = 0; g < 4; ++g) {
        unsigned long long u = *(const unsigned long long*)(
            gxc + ((size_t)(lt + 1) * BB + b_ep) * GG + g * HH + j0 + jj0);
#pragma unroll
        for (int q = 0; q < 4; ++q) gxv[g][q] = bf2f((unsigned short)(u >> (16 * q)));
      }
      cur ^= 1u;
      grid_barrier3(cur);
    }
  }

  // persist c across chunk launches
  {
    float4 cv = {c_reg[0], c_reg[1], c_reg[2], c_reg[3]};
    *(float4*)(c_state + (size_t)b_ep * HH + j0 + jj0) = cv;
  }

  // parity-restoring dummy barrier (keeps global flag state replay-invariant)
  if (tail_bar) { cur ^= 1u; grid_barrier3(cur); }
}

extern "C" void kernel_launch(void* const* d_in, const int* in_sizes, int n_in,
                              void* d_out, int out_size, void* d_ws, size_t ws_size,
                              hipStream_t stream) {
  const float* x       = (const float*)d_in[0];
  const float* w_ih    = (const float*)d_in[1];
  const float* w_hh    = (const float*)d_in[2];
  const float* b_ih    = (const float*)d_in[3];
  const float* b_hh    = (const float*)d_in[4];
  const float* hh_mask = (const float*)d_in[5];
  float* out           = (float*)d_out;

  char* ws = (char*)d_ws;
  float* c_state            = (float*)ws;                       // 262144 B
  unsigned long long* hbuf  = (unsigned long long*)(ws + 262144); // 2*131072 B
  unsigned short* gxc       = (unsigned short*)(ws + 524288);   // chunk buffer

  // adaptive time-chunk: fit chunk gx (TC*B*4H*2 B) in remaining ws, cap at 128 steps
  const size_t per_t = (size_t)BB * GG * 2;                     // 524288 B per step
  long long avail = (ws_size > 524288) ? (long long)(ws_size - 524288) : 0;
  int TC = (int)(avail / (long long)per_t);
  if (TC > 128) TC = 128;
  TC &= ~1;
  if (TC < 2) TC = 2;

  // barrier parity; ensure total barrier count even (replay-invariant flag state)
  unsigned parity = 0;
  int nbar_total = 0;
  for (int t0 = 0; t0 < TT; t0 += TC) {
    int tc = TT - t0 < TC ? TT - t0 : TC;
    nbar_total += tc - 1;
  }
  int need_tail = nbar_total & 1;

  for (int t0 = 0; t0 < TT; t0 += TC) {
    int tc = TT - t0 < TC ? TT - t0 : TC;
    int is_last = (t0 + tc >= TT);
    const float* xc = x + (size_t)t0 * BB * II;
    int grid = (tc * 64 / 128) * 32;
    wdlstm_gemm_gx<<<grid, 256, 0, stream>>>(xc, w_ih, b_ih, b_hh, gxc);
    int tail = is_last ? need_tail : 0;
    wdlstm_recurrence<<<NBLK, 256, 0, stream>>>(w_hh, hh_mask, gxc, out, c_state, hbuf,
                                                t0, tc, parity, tail);
    parity ^= (unsigned)((tc - 1 + tail) & 1);
  }
}

// Round 7
// 4663.079 us; speedup vs baseline: 1.7139x; 1.7139x over previous
//
#include <hip/hip_runtime.h>

#define TT 512
#define BB 64
#define II 1024
#define HH 1024
#define GG 4096   /* 4*H */
#define BH 65536  /* B*H */
#define NBLK 128

typedef __attribute__((ext_vector_type(8))) short bf16x8;
typedef __attribute__((ext_vector_type(4))) float f32x4;

__device__ __forceinline__ float bf2f(unsigned short u) {
  union { unsigned int i; float f; } v; v.i = ((unsigned int)u) << 16; return v.f;
}
__device__ __forceinline__ unsigned short f2bf(float f) {
  union { float f; unsigned int i; } v; v.f = f;
  return (unsigned short)((v.i + 0x7FFFu + ((v.i >> 16) & 1u)) >> 16);
}
__device__ __forceinline__ bf16x8 pack8(float4 a, float4 b) {
  union { bf16x8 v; unsigned short u[8]; } p;
  p.u[0] = f2bf(a.x); p.u[1] = f2bf(a.y); p.u[2] = f2bf(a.z); p.u[3] = f2bf(a.w);
  p.u[4] = f2bf(b.x); p.u[5] = f2bf(b.y); p.u[6] = f2bf(b.z); p.u[7] = f2bf(b.w);
  return p.v;
}
__device__ __forceinline__ float sigmoid_f(float x) { return 1.0f / (1.0f + __expf(-x)); }
__device__ __forceinline__ float tanh_f(float x) {
  float e = __expf(-2.0f * fabsf(x));
  float t = (1.0f - e) / (1.0f + e);
  return copysignf(t, x);
}

__device__ __forceinline__ void st32_uc(unsigned* p, unsigned v) {
  __hip_atomic_store(p, v, __ATOMIC_RELAXED, __HIP_MEMORY_SCOPE_AGENT);
}
__device__ __forceinline__ unsigned ld32_uc(const unsigned* p) {
  return __hip_atomic_load(p, __ATOMIC_RELAXED, __HIP_MEMORY_SCOPE_AGENT);
}

// wait until all NBLK producer flags reach >= t (64 lanes x 2 flags, 64B-padded)
__device__ __forceinline__ void wait_flags(const unsigned* flags, int t) {
  if (threadIdx.x < 64) {
    const unsigned* f0 = flags + (2 * threadIdx.x) * 16;
    const unsigned* f1 = flags + (2 * threadIdx.x + 1) * 16;
    while ((int)ld32_uc(f0) < t || (int)ld32_uc(f1) < t)
      __builtin_amdgcn_s_sleep(1);
  }
  __syncthreads();
}

// ---------------- input GEMM chunk ----------------
// gxc[m][n] = sum_k xc[m][k]*w_ih[n][k] + b_ih[n] + b_hh[n], m in [0, tc*64)
__global__ __launch_bounds__(256) void wdlstm_gemm_gx(
    const float* __restrict__ xc, const float* __restrict__ w_ih,
    const float* __restrict__ b_ih, const float* __restrict__ b_hh,
    unsigned short* __restrict__ gxc) {
  __shared__ __align__(16) char As[16384];  // [128][64] bf16, XOR-swizzled
  __shared__ __align__(16) char Bs[16384];

  const int tid = threadIdx.x;
  const int bx  = blockIdx.x;
  const int tm  = bx >> 5, tn = bx & 31;
  const int m0  = tm * 128, n0 = tn * 128;
  const int wv  = tid >> 6, l = tid & 63;
  const int wr  = wv >> 1, wc = wv & 1;
  const int ln  = l & 15, lq = l >> 4;

  f32x4 acc[4][4];
#pragma unroll
  for (int i = 0; i < 4; ++i)
#pragma unroll
    for (int j = 0; j < 4; ++j) acc[i][j] = (f32x4){0.f, 0.f, 0.f, 0.f};

  for (int kt = 0; kt < 16; ++kt) {
    const int k0 = kt * 64;
    __syncthreads();
#pragma unroll
    for (int o = 0; o < 4; ++o) {
      int c2 = tid + 256 * o;        // 1024 16B-chunks
      int row = c2 >> 3, q8 = c2 & 7;
      int addr = (row * 128 + q8 * 16) ^ ((row & 7) << 4);
      {
        const float* s = xc + (size_t)(m0 + row) * II + k0 + q8 * 8;
        float4 a0 = *(const float4*)s;
        float4 a1 = *(const float4*)(s + 4);
        *(bf16x8*)(As + addr) = pack8(a0, a1);
      }
      {
        const float* s = w_ih + (size_t)(n0 + row) * II + k0 + q8 * 8;
        float4 a0 = *(const float4*)s;
        float4 a1 = *(const float4*)(s + 4);
        *(bf16x8*)(Bs + addr) = pack8(a0, a1);
      }
    }
    __syncthreads();
#pragma unroll
    for (int kc = 0; kc < 2; ++kc) {
      bf16x8 af[4], bfr[4];
#pragma unroll
      for (int mi = 0; mi < 4; ++mi) {
        int row = 64 * wr + 16 * mi + ln;
        int addr = (row * 128 + kc * 64 + lq * 16) ^ ((row & 7) << 4);
        af[mi] = *(const bf16x8*)(As + addr);
      }
#pragma unroll
      for (int ni = 0; ni < 4; ++ni) {
        int row = 64 * wc + 16 * ni + ln;
        int addr = (row * 128 + kc * 64 + lq * 16) ^ ((row & 7) << 4);
        bfr[ni] = *(const bf16x8*)(Bs + addr);
      }
#pragma unroll
      for (int mi = 0; mi < 4; ++mi)
#pragma unroll
        for (int ni = 0; ni < 4; ++ni)
          acc[mi][ni] = __builtin_amdgcn_mfma_f32_16x16x32_bf16(af[mi], bfr[ni], acc[mi][ni], 0, 0, 0);
    }
  }
#pragma unroll
  for (int mi = 0; mi < 4; ++mi)
#pragma unroll
    for (int ni = 0; ni < 4; ++ni) {
      int col = n0 + 64 * wc + 16 * ni + ln;
      float bv = b_ih[col] + b_hh[col];
#pragma unroll
      for (int r = 0; r < 4; ++r) {
        int row = m0 + 64 * wr + 16 * mi + 4 * lq + r;
        gxc[(size_t)row * GG + col] = f2bf(acc[mi][ni][r] + bv);
      }
    }
}

// ---------------- recurrence over one time-chunk [t0, t0+tc) ----------------
// 128 WGs x 256 threads (4 waves). WG owns 8 h-cols (32 gate cols g*8+jj).
// W slice [32][1024] bf16 (64 KB) in LDS. Data-flow sync: per-step per-block
// flags (monotonic global step), h broadcast via never-reused hring slots
// (UC u32 writes, plain cached bf16x8 reads). No grid barrier, no fences.
__global__ __launch_bounds__(256) void wdlstm_recurrence(
    const float* __restrict__ w_hh, const float* __restrict__ hh_mask,
    const unsigned short* __restrict__ gxc,
    float* __restrict__ out, float* __restrict__ c_state,
    unsigned* __restrict__ flags,
    unsigned short* __restrict__ hinit,      // [BH] cross-chunk h carry
    unsigned short* __restrict__ hring,      // [tc][BH] fresh slot per step
    int t0, int tc) {
  __shared__ __align__(16) char Wlds[65536];     // [32][1024] bf16, XOR-swizzled
  __shared__ float Dlds[64][35];                 // 64x32 D, pad 35

  const int tid = threadIdx.x;
  const int wv  = tid >> 6, l = tid & 63;
  const int ln  = l & 15, lq = l >> 4;
  const int j0h = blockIdx.x * 8;

  // preload masked W slice: LDS row n (0..31) = w_hh row (n>>3)*H + j0h + (n&7)
#pragma unroll
  for (int c8 = 0; c8 < 16; ++c8) {
    int c = tid + 256 * c8;          // 4096 chunks of 8 elems
    int n = c >> 7, cc = c & 127;
    int wrow = (n >> 3) * HH + j0h + (n & 7);
    const float* sw = w_hh   + (size_t)wrow * HH + cc * 8;
    const float* sm = hh_mask + (size_t)wrow * HH + cc * 8;
    float4 w0 = *(const float4*)sw, w1 = *(const float4*)(sw + 4);
    float4 m0 = *(const float4*)sm, m1 = *(const float4*)(sm + 4);
    float4 p0 = {w0.x * m0.x, w0.y * m0.y, w0.z * m0.z, w0.w * m0.w};
    float4 p1 = {w1.x * m1.x, w1.y * m1.y, w1.z * m1.z, w1.w * m1.w};
    int addr = (n * 2048 + cc * 16) ^ ((n & 7) << 4);
    *(bf16x8*)(Wlds + addr) = pack8(p0, p1);
  }
  __syncthreads();

  // elementwise ownership: thread (wv, l) -> b = l, cols jj0 = 2*wv (+q, q=0..1)
  const int b_ep = l;
  const int jj0  = 2 * wv;
  float c_reg[2];
  if (t0 == 0) {
    c_reg[0] = c_reg[1] = 0.f;
  } else {
    float2 cv = *(const float2*)(c_state + (size_t)b_ep * HH + j0h + jj0);
    c_reg[0] = cv.x; c_reg[1] = cv.y;
  }

  float* hn_out = out + (size_t)TT * BH;
  float* cn_out = hn_out + BH;

  // prefetch gx for lt=0: 4 gates x 2 cols (cached u32)
  float gxv[4][2];
#pragma unroll
  for (int g = 0; g < 4; ++g) {
    unsigned u = *(const unsigned*)(gxc + (size_t)b_ep * GG + g * HH + j0h + jj0);
    gxv[g][0] = bf2f((unsigned short)u);
    gxv[g][1] = bf2f((unsigned short)(u >> 16));
  }

  for (int lt = 0; lt < tc; ++lt) {
    const int t = t0 + lt;

    f32x4 acc[2];
    acc[0] = (f32x4){0.f, 0.f, 0.f, 0.f};
    acc[1] = (f32x4){0.f, 0.f, 0.f, 0.f};

    if (t > 0) {
      wait_flags(flags, t);          // all producers finished h(t-1)
      const unsigned short* hp = (lt == 0) ? hinit
                                           : hring + (size_t)(lt - 1) * BH;
      const unsigned short* ap = hp + (size_t)(16 * wv + ln) * HH + lq * 8;
#pragma unroll 4
      for (int kc = 0; kc < 32; ++kc) {
        bf16x8 a = *(const bf16x8*)(ap + kc * 32);   // cached, coalesced
#pragma unroll
        for (int ni = 0; ni < 2; ++ni) {
          int n = 16 * ni + ln;
          int baddr = (n * 2048 + kc * 64 + lq * 16) ^ ((n & 7) << 4);
          bf16x8 b = *(const bf16x8*)(Wlds + baddr);
          acc[ni] = __builtin_amdgcn_mfma_f32_16x16x32_bf16(a, b, acc[ni], 0, 0, 0);
        }
      }
    }
    // transpose D through LDS: wave wv rows 16wv+4lq+r, cols 16ni+ln
#pragma unroll
    for (int ni = 0; ni < 2; ++ni)
#pragma unroll
      for (int r = 0; r < 4; ++r)
        Dlds[16 * wv + 4 * lq + r][16 * ni + ln] = acc[ni][r];
    __syncthreads();

    // ---- elementwise: 2 states per thread; D col n = g*8 + jj
    float hq[2];
#pragma unroll
    for (int q = 0; q < 2; ++q) {
      float g0 = Dlds[b_ep][ 0 + jj0 + q] + gxv[0][q];
      float g1 = Dlds[b_ep][ 8 + jj0 + q] + gxv[1][q];
      float g2 = Dlds[b_ep][16 + jj0 + q] + gxv[2][q];
      float g3 = Dlds[b_ep][24 + jj0 + q] + gxv[3][q];
      float ig = sigmoid_f(g0);
      float fg = sigmoid_f(g1);
      float gg = tanh_f(g2);
      float og = sigmoid_f(g3);
      c_reg[q] = fg * c_reg[q] + ig * gg;
      hq[q] = og * tanh_f(c_reg[q]);
    }
    *(float2*)(out + (size_t)t * BH + (size_t)b_ep * HH + j0h + jj0) = make_float2(hq[0], hq[1]);
    unsigned hpack = (unsigned)f2bf(hq[0]) | ((unsigned)f2bf(hq[1]) << 16);
    unsigned* hr32 = (unsigned*)(hring + (size_t)lt * BH);
    st32_uc(hr32 + (((size_t)b_ep * HH + j0h + jj0) >> 1), hpack);
    if (lt == tc - 1) {  // cross-chunk carry (read once at next dispatch's start)
      unsigned* hi32 = (unsigned*)hinit;
      st32_uc(hi32 + (((size_t)b_ep * HH + j0h + jj0) >> 1), hpack);
    }
    if (t == TT - 1) {
      *(float2*)(hn_out + (size_t)b_ep * HH + j0h + jj0) = make_float2(hq[0], hq[1]);
      *(float2*)(cn_out + (size_t)b_ep * HH + j0h + jj0) = make_float2(c_reg[0], c_reg[1]);
    }

    // prefetch next step's gx (cached; overlaps the store drain)
    if (lt + 1 < tc) {
#pragma unroll
      for (int g = 0; g < 4; ++g) {
        unsigned u = *(const unsigned*)(gxc + ((size_t)(lt + 1) * BB + b_ep) * GG + g * HH + j0h + jj0);
        gxv[g][0] = bf2f((unsigned short)u);
        gxv[g][1] = bf2f((unsigned short)(u >> 16));
      }
    }

    // drain this block's h stores (syncthreads implies per-wave vmcnt(0) drain),
    // then publish flag = t+1
    __syncthreads();
    if (tid == 0) st32_uc(&flags[blockIdx.x * 16], (unsigned)(t + 1));
  }

  // persist c across chunk launches
  *(float2*)(c_state + (size_t)b_ep * HH + j0h + jj0) = make_float2(c_reg[0], c_reg[1]);
}

extern "C" void kernel_launch(void* const* d_in, const int* in_sizes, int n_in,
                              void* d_out, int out_size, void* d_ws, size_t ws_size,
                              hipStream_t stream) {
  const float* x       = (const float*)d_in[0];
  const float* w_ih    = (const float*)d_in[1];
  const float* w_hh    = (const float*)d_in[2];
  const float* b_ih    = (const float*)d_in[3];
  const float* b_hh    = (const float*)d_in[4];
  const float* hh_mask = (const float*)d_in[5];
  float* out           = (float*)d_out;

  char* ws = (char*)d_ws;
  float* c_state        = (float*)ws;                           // 262144 B
  unsigned* flags       = (unsigned*)(ws + 262144);             // 16384 B (128 x 64B, padded)
  unsigned short* hinit = (unsigned short*)(ws + 278528);       // 131072 B
  unsigned short* hring = (unsigned short*)(ws + 409600);       // TC x 131072 B
  // gxc placed after hring (TC-dependent)

  // adaptive time-chunk: per step needs 512KB (gx) + 128KB (hring slot)
  const long long fixed = 409600;
  const long long per_t = 524288 + 131072;
  long long avail = (long long)ws_size - fixed;
  int TC = (int)(avail / per_t);
  if (TC > 128) TC = 128;
  TC &= ~1;
  if (TC < 2) TC = 2;
  unsigned short* gxc = (unsigned short*)(ws + 409600 + (size_t)TC * 131072);

  // reset flags once per launch (graph-capture-safe async memset)
  hipMemsetAsync(flags, 0, 16384, stream);

  for (int t0 = 0; t0 < TT; t0 += TC) {
    int tc = TT - t0 < TC ? TT - t0 : TC;
    const float* xc = x + (size_t)t0 * BB * II;
    int grid = (tc * 64 / 128) * 32;
    wdlstm_gemm_gx<<<grid, 256, 0, stream>>>(xc, w_ih, b_ih, b_hh, gxc);
    wdlstm_recurrence<<<NBLK, 256, 0, stream>>>(w_hh, hh_mask, gxc, out, c_state,
                                                flags, hinit, hring, t0, tc);
  }
}

// Round 8
// 4539.375 us; speedup vs baseline: 1.7607x; 1.0273x over previous
//
#include <hip/hip_runtime.h>

#define TT 512
#define BB 64
#define II 1024
#define HH 1024
#define GG 4096   /* 4*H */
#define BH 65536  /* B*H */
#define NBLK 128

typedef __attribute__((ext_vector_type(8))) short bf16x8;
typedef __attribute__((ext_vector_type(4))) float f32x4;
typedef __attribute__((ext_vector_type(4))) unsigned u32x4;

__device__ __forceinline__ float bf2f(unsigned short u) {
  union { unsigned int i; float f; } v; v.i = ((unsigned int)u) << 16; return v.f;
}
__device__ __forceinline__ unsigned short f2bf(float f) {
  union { float f; unsigned int i; } v; v.f = f;
  return (unsigned short)((v.i + 0x7FFFu + ((v.i >> 16) & 1u)) >> 16);
}
__device__ __forceinline__ bf16x8 pack8(float4 a, float4 b) {
  union { bf16x8 v; unsigned short u[8]; } p;
  p.u[0] = f2bf(a.x); p.u[1] = f2bf(a.y); p.u[2] = f2bf(a.z); p.u[3] = f2bf(a.w);
  p.u[4] = f2bf(b.x); p.u[5] = f2bf(b.y); p.u[6] = f2bf(b.z); p.u[7] = f2bf(b.w);
  return p.v;
}
__device__ __forceinline__ float sigmoid_f(float x) { return 1.0f / (1.0f + __expf(-x)); }
__device__ __forceinline__ float tanh_f(float x) {
  float e = __expf(-2.0f * fabsf(x));
  float t = (1.0f - e) / (1.0f + e);
  return copysignf(t, x);
}

__device__ __forceinline__ void st32_uc(unsigned* p, unsigned v) {
  __hip_atomic_store(p, v, __ATOMIC_RELAXED, __HIP_MEMORY_SCOPE_AGENT);
}
__device__ __forceinline__ unsigned ld32_uc(const unsigned* p) {
  return __hip_atomic_load(p, __ATOMIC_RELAXED, __HIP_MEMORY_SCOPE_AGENT);
}
// 16B write-through to the coherence point (non-atomic; aligned 16B = 1 transaction)
__device__ __forceinline__ void st128_uc(void* p, u32x4 v) {
  asm volatile("global_store_dwordx4 %0, %1, off sc0 sc1" :: "v"(p), "v"(v) : "memory");
}

// ---------------- input GEMM chunk ----------------
// gxc[m][n] = sum_k xc[m][k]*w_ih[n][k] + b_ih[n] + b_hh[n], m in [0, tc*64)
__global__ __launch_bounds__(256) void wdlstm_gemm_gx(
    const float* __restrict__ xc, const float* __restrict__ w_ih,
    const float* __restrict__ b_ih, const float* __restrict__ b_hh,
    unsigned short* __restrict__ gxc) {
  __shared__ __align__(16) char As[16384];  // [128][64] bf16, XOR-swizzled
  __shared__ __align__(16) char Bs[16384];

  const int tid = threadIdx.x;
  const int bx  = blockIdx.x;
  const int tm  = bx >> 5, tn = bx & 31;
  const int m0  = tm * 128, n0 = tn * 128;
  const int wv  = tid >> 6, l = tid & 63;
  const int wr  = wv >> 1, wc = wv & 1;
  const int ln  = l & 15, lq = l >> 4;

  f32x4 acc[4][4];
#pragma unroll
  for (int i = 0; i < 4; ++i)
#pragma unroll
    for (int j = 0; j < 4; ++j) acc[i][j] = (f32x4){0.f, 0.f, 0.f, 0.f};

  for (int kt = 0; kt < 16; ++kt) {
    const int k0 = kt * 64;
    __syncthreads();
#pragma unroll
    for (int o = 0; o < 4; ++o) {
      int c2 = tid + 256 * o;        // 1024 16B-chunks
      int row = c2 >> 3, q8 = c2 & 7;
      int addr = (row * 128 + q8 * 16) ^ ((row & 7) << 4);
      {
        const float* s = xc + (size_t)(m0 + row) * II + k0 + q8 * 8;
        float4 a0 = *(const float4*)s;
        float4 a1 = *(const float4*)(s + 4);
        *(bf16x8*)(As + addr) = pack8(a0, a1);
      }
      {
        const float* s = w_ih + (size_t)(n0 + row) * II + k0 + q8 * 8;
        float4 a0 = *(const float4*)s;
        float4 a1 = *(const float4*)(s + 4);
        *(bf16x8*)(Bs + addr) = pack8(a0, a1);
      }
    }
    __syncthreads();
#pragma unroll
    for (int kc = 0; kc < 2; ++kc) {
      bf16x8 af[4], bfr[4];
#pragma unroll
      for (int mi = 0; mi < 4; ++mi) {
        int row = 64 * wr + 16 * mi + ln;
        int addr = (row * 128 + kc * 64 + lq * 16) ^ ((row & 7) << 4);
        af[mi] = *(const bf16x8*)(As + addr);
      }
#pragma unroll
      for (int ni = 0; ni < 4; ++ni) {
        int row = 64 * wc + 16 * ni + ln;
        int addr = (row * 128 + kc * 64 + lq * 16) ^ ((row & 7) << 4);
        bfr[ni] = *(const bf16x8*)(Bs + addr);
      }
#pragma unroll
      for (int mi = 0; mi < 4; ++mi)
#pragma unroll
        for (int ni = 0; ni < 4; ++ni)
          acc[mi][ni] = __builtin_amdgcn_mfma_f32_16x16x32_bf16(af[mi], bfr[ni], acc[mi][ni], 0, 0, 0);
    }
  }
#pragma unroll
  for (int mi = 0; mi < 4; ++mi)
#pragma unroll
    for (int ni = 0; ni < 4; ++ni) {
      int col = n0 + 64 * wc + 16 * ni + ln;
      float bv = b_ih[col] + b_hh[col];
#pragma unroll
      for (int r = 0; r < 4; ++r) {
        int row = m0 + 64 * wr + 16 * mi + 4 * lq + r;
        gxc[(size_t)row * GG + col] = f2bf(acc[mi][ni][r] + bv);
      }
    }
}

// ---------------- recurrence over one time-chunk [t0, t0+tc) ----------------
// 128 WGs x 256 threads (4 waves). WG owns 8 h-cols (32 gate cols g*8+jj).
// W slice [32][1024] bf16 (64 KB) in LDS. Data-flow sync, hierarchical:
// producers UC-store flag[b]=t+1 after h(t) visible; block 0 aggregates flags
// and publishes g_step=t; consumers poll the single g_step word.
// h broadcast via never-reused hring slots: LDS-gathered, wave 0 stores 16B
// write-through (sc0 sc1) lines; consumers use plain cached reads (fresh lines).
__global__ __launch_bounds__(256) void wdlstm_recurrence(
    const float* __restrict__ w_hh, const float* __restrict__ hh_mask,
    const unsigned short* __restrict__ gxc,
    float* __restrict__ out, float* __restrict__ c_state,
    unsigned* __restrict__ flags,            // [NBLK] 64B-padded + g_step at +8192B
    unsigned short* __restrict__ hinit,      // [BH] cross-chunk h carry
    unsigned short* __restrict__ hring,      // [tc][BH] fresh slot per step
    int t0, int tc) {
  __shared__ __align__(16) char Wlds[65536];     // [32][1024] bf16, XOR-swizzled
  __shared__ float Dlds[64][35];                 // 64x32 D, pad 35
  __shared__ __align__(16) unsigned Hs[64][4];   // block's h-slice, packed bf16x2

  const int tid = threadIdx.x;
  const int wv  = tid >> 6, l = tid & 63;
  const int ln  = l & 15, lq = l >> 4;
  const int j0h = blockIdx.x * 8;
  unsigned* g_step = flags + 2048;               // +8192 B

  // preload masked W slice: LDS row n (0..31) = w_hh row (n>>3)*H + j0h + (n&7)
#pragma unroll
  for (int c8 = 0; c8 < 16; ++c8) {
    int c = tid + 256 * c8;          // 4096 chunks of 8 elems
    int n = c >> 7, cc = c & 127;
    int wrow = (n >> 3) * HH + j0h + (n & 7);
    const float* sw = w_hh   + (size_t)wrow * HH + cc * 8;
    const float* sm = hh_mask + (size_t)wrow * HH + cc * 8;
    float4 w0 = *(const float4*)sw, w1 = *(const float4*)(sw + 4);
    float4 m0 = *(const float4*)sm, m1 = *(const float4*)(sm + 4);
    float4 p0 = {w0.x * m0.x, w0.y * m0.y, w0.z * m0.z, w0.w * m0.w};
    float4 p1 = {w1.x * m1.x, w1.y * m1.y, w1.z * m1.z, w1.w * m1.w};
    int addr = (n * 2048 + cc * 16) ^ ((n & 7) << 4);
    *(bf16x8*)(Wlds + addr) = pack8(p0, p1);
  }
  __syncthreads();

  // elementwise ownership: thread (wv, l) -> b = l, cols jj0 = 2*wv (+q, q=0..1)
  const int b_ep = l;
  const int jj0  = 2 * wv;
  float c_reg[2];
  if (t0 == 0) {
    c_reg[0] = c_reg[1] = 0.f;
  } else {
    float2 cv = *(const float2*)(c_state + (size_t)b_ep * HH + j0h + jj0);
    c_reg[0] = cv.x; c_reg[1] = cv.y;
  }

  float* hn_out = out + (size_t)TT * BH;
  float* cn_out = hn_out + BH;

  // prefetch gx for lt=0: 4 gates x 2 cols (cached u32)
  float gxv[4][2];
#pragma unroll
  for (int g = 0; g < 4; ++g) {
    unsigned u = *(const unsigned*)(gxc + (size_t)b_ep * GG + g * HH + j0h + jj0);
    gxv[g][0] = bf2f((unsigned short)u);
    gxv[g][1] = bf2f((unsigned short)(u >> 16));
  }

  for (int lt = 0; lt < tc; ++lt) {
    const int t = t0 + lt;

    f32x4 acc[2];
    acc[0] = (f32x4){0.f, 0.f, 0.f, 0.f};
    acc[1] = (f32x4){0.f, 0.f, 0.f, 0.f};

    if (t > 0) {
      // ---- wait for h(t-1): hierarchical ----
      if (blockIdx.x == 0) {
        if (tid < 64) {        // wave 0: poll two flags per lane
          const unsigned* f0 = flags + (2 * tid) * 16;
          const unsigned* f1 = flags + (2 * tid + 1) * 16;
          while ((int)ld32_uc(f0) < t || (int)ld32_uc(f1) < t)
            __builtin_amdgcn_s_sleep(1);
          if (tid == 0) st32_uc(g_step, (unsigned)t);   // wave-synchronous after polls
        }
        __syncthreads();
      } else {
        if (tid == 0) {
          while ((int)ld32_uc(g_step) < t) __builtin_amdgcn_s_sleep(1);
        }
        __syncthreads();
      }

      const unsigned short* hp = (lt == 0) ? hinit
                                           : hring + (size_t)(lt - 1) * BH;
      const unsigned short* ap = hp + (size_t)(16 * wv + ln) * HH + lq * 8;
#pragma unroll 4
      for (int kc = 0; kc < 32; ++kc) {
        bf16x8 a = *(const bf16x8*)(ap + kc * 32);   // cached, coalesced
#pragma unroll
        for (int ni = 0; ni < 2; ++ni) {
          int n = 16 * ni + ln;
          int baddr = (n * 2048 + kc * 64 + lq * 16) ^ ((n & 7) << 4);
          bf16x8 b = *(const bf16x8*)(Wlds + baddr);
          acc[ni] = __builtin_amdgcn_mfma_f32_16x16x32_bf16(a, b, acc[ni], 0, 0, 0);
        }
      }
    }
    // transpose D through LDS: wave wv rows 16wv+4lq+r, cols 16ni+ln
#pragma unroll
    for (int ni = 0; ni < 2; ++ni)
#pragma unroll
      for (int r = 0; r < 4; ++r)
        Dlds[16 * wv + 4 * lq + r][16 * ni + ln] = acc[ni][r];
    __syncthreads();

    // ---- elementwise: 2 states per thread; D col n = g*8 + jj
    float hq[2];
#pragma unroll
    for (int q = 0; q < 2; ++q) {
      float g0 = Dlds[b_ep][ 0 + jj0 + q] + gxv[0][q];
      float g1 = Dlds[b_ep][ 8 + jj0 + q] + gxv[1][q];
      float g2 = Dlds[b_ep][16 + jj0 + q] + gxv[2][q];
      float g3 = Dlds[b_ep][24 + jj0 + q] + gxv[3][q];
      float ig = sigmoid_f(g0);
      float fg = sigmoid_f(g1);
      float gg = tanh_f(g2);
      float og = sigmoid_f(g3);
      c_reg[q] = fg * c_reg[q] + ig * gg;
      hq[q] = og * tanh_f(c_reg[q]);
    }
    *(float2*)(out + (size_t)t * BH + (size_t)b_ep * HH + j0h + jj0) = make_float2(hq[0], hq[1]);
    Hs[b_ep][wv] = (unsigned)f2bf(hq[0]) | ((unsigned)f2bf(hq[1]) << 16);
    if (t == TT - 1) {
      *(float2*)(hn_out + (size_t)b_ep * HH + j0h + jj0) = make_float2(hq[0], hq[1]);
      *(float2*)(cn_out + (size_t)b_ep * HH + j0h + jj0) = make_float2(c_reg[0], c_reg[1]);
    }

    // prefetch next step's gx (cached; overlaps publish)
    if (lt + 1 < tc) {
#pragma unroll
      for (int g = 0; g < 4; ++g) {
        unsigned u = *(const unsigned*)(gxc + ((size_t)(lt + 1) * BB + b_ep) * GG + g * HH + j0h + jj0);
        gxv[g][0] = bf2f((unsigned short)u);
        gxv[g][1] = bf2f((unsigned short)(u >> 16));
      }
    }

    __syncthreads();   // Hs complete; Dlds consumed (safe to overwrite next iter)

    // ---- publish: wave 0 stores the block's 64x8 h-slice as 64 x 16B UC lines
    if (wv == 0) {
      u32x4 hv4 = *(const u32x4*)&Hs[l][0];
      char* dst = (char*)hring + ((size_t)lt * BH + (size_t)l * HH + j0h) * 2;
      st128_uc(dst, hv4);
      if (lt == tc - 1) {   // cross-chunk carry
        char* dsti = (char*)hinit + ((size_t)l * HH + j0h) * 2;
        st128_uc(dsti, hv4);
      }
      asm volatile("s_waitcnt vmcnt(0)" ::: "memory");
      if (tid == 0) st32_uc(&flags[blockIdx.x * 16], (unsigned)(t + 1));
    }
  }

  // persist c across chunk launches
  *(float2*)(c_state + (size_t)b_ep * HH + j0h + jj0) = make_float2(c_reg[0], c_reg[1]);
}

extern "C" void kernel_launch(void* const* d_in, const int* in_sizes, int n_in,
                              void* d_out, int out_size, void* d_ws, size_t ws_size,
                              hipStream_t stream) {
  const float* x       = (const float*)d_in[0];
  const float* w_ih    = (const float*)d_in[1];
  const float* w_hh    = (const float*)d_in[2];
  const float* b_ih    = (const float*)d_in[3];
  const float* b_hh    = (const float*)d_in[4];
  const float* hh_mask = (const float*)d_in[5];
  float* out           = (float*)d_out;

  char* ws = (char*)d_ws;
  float* c_state        = (float*)ws;                           // 262144 B
  unsigned* flags       = (unsigned*)(ws + 262144);             // 16384 B (128x64B + g_step)
  unsigned short* hinit = (unsigned short*)(ws + 278528);       // 131072 B
  unsigned short* hring = (unsigned short*)(ws + 409600);       // TC x 131072 B

  // adaptive time-chunk: per step needs 512KB (gx) + 128KB (hring slot)
  const long long fixed = 409600;
  const long long per_t = 524288 + 131072;
  long long avail = (long long)ws_size - fixed;
  int TC = (int)(avail / per_t);
  if (TC > 128) TC = 128;
  TC &= ~1;
  if (TC < 2) TC = 2;
  unsigned short* gxc = (unsigned short*)(ws + 409600 + (size_t)TC * 131072);

  // reset flags + g_step once per launch (graph-capture-safe async memset)
  hipMemsetAsync(flags, 0, 16384, stream);

  for (int t0 = 0; t0 < TT; t0 += TC) {
    int tc = TT - t0 < TC ? TT - t0 : TC;
    const float* xc = x + (size_t)t0 * BB * II;
    int grid = (tc * 64 / 128) * 32;
    wdlstm_gemm_gx<<<grid, 256, 0, stream>>>(xc, w_ih, b_ih, b_hh, gxc);
    wdlstm_recurrence<<<NBLK, 256, 0, stream>>>(w_hh, hh_mask, gxc, out, c_state,
                                                flags, hinit, hring, t0, tc);
  }
}